// Round 2
// baseline (228.441 us; speedup 1.0000x reference)
//
#include <hip/hip_runtime.h>

// Reference: out = x @ eye(4096) == x. Pure float32 copy, memory-bound.
// 8192*4096 floats = 33,554,432 elements = 8,388,608 float4s.
// Traffic: 134.2 MB read + 134.2 MB write = 268.4 MB -> ~42.7 us at 6.29 TB/s.
//
// 4x 16B per thread, all 4 loads issued before any store (4-deep MLP per
// lane), no per-element bounds check on the fast path (n4 % 1024 == 0 here:
// 8,388,608 / 1024 = 8192 blocks exactly), and non-temporal stores so the
// write stream is evict-first in L2/L3 (output never re-read in the timed
// region). NOTE: __builtin_nontemporal_store requires a NATIVE vector type,
// not HIP_vector_type<float,4> -> use clang ext_vector_type(4).

typedef float vf4 __attribute__((ext_vector_type(4)));

constexpr int BLOCK = 256;
constexpr int F4_PER_THREAD = 4;
constexpr int F4_PER_BLOCK = BLOCK * F4_PER_THREAD;  // 1024 float4s = 16 KiB

__global__ __launch_bounds__(BLOCK) void copy_f4x4(const vf4* __restrict__ in,
                                                   vf4* __restrict__ out) {
    int base = blockIdx.x * F4_PER_BLOCK + threadIdx.x;
    // 4 independent loads in flight before any store (coalesced: lane i hits
    // base+i within each 256-wide slab).
    vf4 a = in[base];
    vf4 b = in[base + BLOCK];
    vf4 c = in[base + 2 * BLOCK];
    vf4 d = in[base + 3 * BLOCK];
    __builtin_nontemporal_store(a, &out[base]);
    __builtin_nontemporal_store(b, &out[base + BLOCK]);
    __builtin_nontemporal_store(c, &out[base + 2 * BLOCK]);
    __builtin_nontemporal_store(d, &out[base + 3 * BLOCK]);
}

// Guarded fallback for any tail (not taken for this problem's sizes).
__global__ __launch_bounds__(BLOCK) void copy_f4_tail(const vf4* __restrict__ in,
                                                      vf4* __restrict__ out,
                                                      int start, int n4) {
    int i = start + blockIdx.x * blockDim.x + threadIdx.x;
    if (i < n4) {
        vf4 v = in[i];
        __builtin_nontemporal_store(v, &out[i]);
    }
}

extern "C" void kernel_launch(void* const* d_in, const int* in_sizes, int n_in,
                              void* d_out, int out_size, void* d_ws, size_t ws_size,
                              hipStream_t stream) {
    const vf4* x = (const vf4*)d_in[0];
    vf4* out = (vf4*)d_out;
    int n4 = out_size / 4;  // 8,388,608 float4s

    int main_blocks = n4 / F4_PER_BLOCK;          // 8192 for this problem
    int main_n4 = main_blocks * F4_PER_BLOCK;     // == n4 here

    if (main_blocks > 0) {
        copy_f4x4<<<main_blocks, BLOCK, 0, stream>>>(x, out);
    }
    int tail = n4 - main_n4;                      // 0 for this problem
    if (tail > 0) {
        int tail_blocks = (tail + BLOCK - 1) / BLOCK;
        copy_f4_tail<<<tail_blocks, BLOCK, 0, stream>>>(x, out, main_n4, n4);
    }
}

// Round 3
// 225.454 us; speedup vs baseline: 1.0132x; 1.0132x over previous
//
#include <hip/hip_runtime.h>

// Reference: out = x @ eye(4096) == x. Pure float32 copy, memory-bound.
// 8192*4096 floats = 33,554,432 elements = 8,388,608 float4s.
// Traffic: 134.2 MB read + 134.2 MB write = 268.4 MB -> ~42.7 us at 6.29 TB/s.
//
// Round-2 A/B: Round-1 bundled {4x unroll + nontemporal stores} and regressed
// 217.5 -> 228.4 us. This version keeps the 4x unroll (4 loads in flight
// before any store = 4-deep MLP per lane) and REVERTS the nt stores to plain
// global_store_dwordx4, isolating nt as the suspected regression cause.
// n4 % 1024 == 0 (8,388,608 / 1024 = 8192 blocks), so the fast path has no
// bounds check; a guarded tail kernel covers other shapes.

typedef float vf4 __attribute__((ext_vector_type(4)));

constexpr int BLOCK = 256;
constexpr int F4_PER_THREAD = 4;
constexpr int F4_PER_BLOCK = BLOCK * F4_PER_THREAD;  // 1024 float4s = 16 KiB

__global__ __launch_bounds__(BLOCK) void copy_f4x4(const vf4* __restrict__ in,
                                                   vf4* __restrict__ out) {
    int base = blockIdx.x * F4_PER_BLOCK + threadIdx.x;
    // 4 independent loads issued back-to-back (coalesced: lane i hits base+i
    // within each 256-wide slab), then 4 plain stores.
    vf4 a = in[base];
    vf4 b = in[base + BLOCK];
    vf4 c = in[base + 2 * BLOCK];
    vf4 d = in[base + 3 * BLOCK];
    out[base] = a;
    out[base + BLOCK] = b;
    out[base + 2 * BLOCK] = c;
    out[base + 3 * BLOCK] = d;
}

// Guarded fallback for any tail (not taken for this problem's sizes).
__global__ __launch_bounds__(BLOCK) void copy_f4_tail(const vf4* __restrict__ in,
                                                      vf4* __restrict__ out,
                                                      int start, int n4) {
    int i = start + blockIdx.x * blockDim.x + threadIdx.x;
    if (i < n4) {
        out[i] = in[i];
    }
}

extern "C" void kernel_launch(void* const* d_in, const int* in_sizes, int n_in,
                              void* d_out, int out_size, void* d_ws, size_t ws_size,
                              hipStream_t stream) {
    const vf4* x = (const vf4*)d_in[0];
    vf4* out = (vf4*)d_out;
    int n4 = out_size / 4;  // 8,388,608 float4s

    int main_blocks = n4 / F4_PER_BLOCK;          // 8192 for this problem
    int main_n4 = main_blocks * F4_PER_BLOCK;     // == n4 here

    if (main_blocks > 0) {
        copy_f4x4<<<main_blocks, BLOCK, 0, stream>>>(x, out);
    }
    int tail = n4 - main_n4;                      // 0 for this problem
    if (tail > 0) {
        int tail_blocks = (tail + BLOCK - 1) / BLOCK;
        copy_f4_tail<<<tail_blocks, BLOCK, 0, stream>>>(x, out, main_n4, n4);
    }
}